// Round 4
// baseline (318.907 us; speedup 1.0000x reference)
//
#include <hip/hip_runtime.h>
#include <math.h>

// Problem constants (fixed by the reference's setup_inputs)
#define OUTS 7
#define NBIN 49            // 7*7 output bins
#define NCH 256
#define CPB 64             // channels per block
#define NCGRP 5            // floor(256 threads / 49 bins)

__global__ __launch_bounds__(256) void roi_extract_kernel(
    const float* __restrict__ f0, const float* __restrict__ f1,
    const float* __restrict__ f2, const float* __restrict__ f3,
    const float* __restrict__ rois, float* __restrict__ out, int K)
{
    const int k = blockIdx.x;
    if (k >= K) return;
    const int cbase = blockIdx.y * CPB;
    const int tid = threadIdx.x;
    const int cgrp = tid / NBIN;           // 0..5
    const int bin  = tid - cgrp * NBIN;    // 0..48
    if (cgrp >= NCGRP) return;             // 11 idle threads; no barriers anywhere

    // RoI scalars (uniform per block -> scalar loads)
    const float rx1 = rois[0 * K + k];
    const float ry1 = rois[1 * K + k];
    const float rx2 = rois[2 * K + k];
    const float ry2 = rois[3 * K + k];

    // FPN level: floor(log2(sqrt(area)/56 + 1e-6)), clipped to [0,3]
    const float sroi = sqrtf((rx2 - rx1 + 1.0f) * (ry2 - ry1 + 1.0f));
    int lv = (int)floorf(log2f(sroi / 56.0f + 1e-6f));
    lv = lv < 0 ? 0 : (lv > 3 ? 3 : lv);

    const float* fbase; int H, W; float sc;
    switch (lv) {
        case 0:  fbase = f0; H = 200; W = 304; sc = 0.25f;    break;
        case 1:  fbase = f1; H = 100; W = 152; sc = 0.125f;   break;
        case 2:  fbase = f2; H = 50;  W = 76;  sc = 0.0625f;  break;
        default: fbase = f3; H = 25;  W = 38;  sc = 0.03125f; break;
    }
    const int HW = H * W;

    const int oh = bin / OUTS;
    const int ow = bin - oh * OUTS;

    // Per-thread sample geometry (computed once; reference numerics)
    const float y1s = ry1 * sc;
    const float roih = fmaxf(ry2 * sc - y1s, 1.0f);
    const float x1s = rx1 * sc;
    const float roiw = fmaxf(rx2 * sc - x1s, 1.0f);

    int yo0[2], yo1[2]; float wy[2], vy[2];
#pragma unroll
    for (int py = 0; py < 2; ++py) {
        const int s = oh * 2 + py;
        const float g = ((float)s + 0.5f) * 0.5f;          // (s+0.5)/RATIO
        const float ys = y1s + g * (roih / (float)OUTS);
        vy[py] = (ys >= -1.0f && ys <= (float)H) ? 1.0f : 0.0f;
        const float y = fminf(fmaxf(ys, 0.0f), (float)(H - 1));
        const float y0f = floorf(y);
        const int y0 = (int)y0f;
        yo0[py] = y0 * W;
        yo1[py] = min(y0 + 1, H - 1) * W;
        wy[py] = y - y0f;
    }
    int xo0[2], xo1[2]; float wx[2], vx[2];
#pragma unroll
    for (int px = 0; px < 2; ++px) {
        const int s = ow * 2 + px;
        const float g = ((float)s + 0.5f) * 0.5f;
        const float xs = x1s + g * (roiw / (float)OUTS);
        vx[px] = (xs >= -1.0f && xs <= (float)W) ? 1.0f : 0.0f;
        const float x = fminf(fmaxf(xs, 0.0f), (float)(W - 1));
        const float x0f = floorf(x);
        const int x0 = (int)x0f;
        xo0[px] = x0;
        xo1[px] = min(x0 + 1, W - 1);
        wx[px] = x - x0f;
    }

    // 16 (offset, weight) tap pairs; validity and the /4 sample-average folded in
    int off[16]; float wt[16];
#pragma unroll
    for (int py = 0; py < 2; ++py) {
#pragma unroll
        for (int px = 0; px < 2; ++px) {
            const int i = (py * 2 + px) * 4;
            const float v = vy[py] * vx[px] * 0.25f;
            const float a = wy[py], b = wx[px];
            off[i + 0] = yo0[py] + xo0[px]; wt[i + 0] = (1.0f - a) * (1.0f - b) * v;
            off[i + 1] = yo0[py] + xo1[px]; wt[i + 1] = (1.0f - a) * b * v;
            off[i + 2] = yo1[py] + xo0[px]; wt[i + 2] = a * (1.0f - b) * v;
            off[i + 3] = yo1[py] + xo1[px]; wt[i + 3] = a * b * v;
        }
    }

    // Channel loop: ~13 channels/thread, body = 16 independent loads + FMAs
    const float* fc = fbase + (size_t)(cbase + cgrp) * HW;
    float* op = out + ((size_t)k * NCH + (size_t)(cbase + cgrp)) * NBIN + bin;
    const size_t fstep = (size_t)NCGRP * HW;
    const size_t ostep = (size_t)NCGRP * NBIN;
#pragma unroll 2
    for (int c = cgrp; c < CPB; c += NCGRP) {
        float acc = 0.0f;
#pragma unroll
        for (int i = 0; i < 16; ++i) acc += fc[off[i]] * wt[i];
        *op = acc;
        fc += fstep;
        op += ostep;
    }
}

extern "C" void kernel_launch(void* const* d_in, const int* in_sizes, int n_in,
                              void* d_out, int out_size, void* d_ws, size_t ws_size,
                              hipStream_t stream) {
    const float* f0 = (const float*)d_in[0];
    const float* f1 = (const float*)d_in[1];
    const float* f2 = (const float*)d_in[2];
    const float* f3 = (const float*)d_in[3];
    const float* rois = (const float*)d_in[4];
    float* out = (float*)d_out;
    int K = in_sizes[4] / 4;
    if (K <= 0) return;

    dim3 grid(K, NCH / CPB);   // (1024, 4)
    roi_extract_kernel<<<grid, 256, 0, stream>>>(f0, f1, f2, f3, rois, out, K);
}

// Round 5
// 227.883 us; speedup vs baseline: 1.3994x; 1.3994x over previous
//
#include <hip/hip_runtime.h>
#include <math.h>

#define OUTS 7
#define NBIN 49
#define NCH 256
#define CPB 32           // channels per block; grid.y = 8
#define LDSW 1200        // float2 elements per wave window (worst-case E ~1060)

__global__ __launch_bounds__(256) void roi_extract_kernel(
    const float* __restrict__ f0, const float* __restrict__ f1,
    const float* __restrict__ f2, const float* __restrict__ f3,
    const float* __restrict__ rois, float* __restrict__ out, int K)
{
    const int k = blockIdx.x;
    if (k >= K) return;
    const int cbase = blockIdx.y * CPB;
    const int tid = threadIdx.x;
    const int wid = tid >> 6;           // wave 0..3
    const int lane = tid & 63;
    const int bin = lane < NBIN ? lane : NBIN - 1;   // clamp for lanes 49..63

    // ---- RoI scalars (uniform per block) ----
    const float rx1 = rois[0 * K + k];
    const float ry1 = rois[1 * K + k];
    const float rx2 = rois[2 * K + k];
    const float ry2 = rois[3 * K + k];

    const float sroi = sqrtf((rx2 - rx1 + 1.0f) * (ry2 - ry1 + 1.0f));
    int lv = (int)floorf(log2f(sroi / 56.0f + 1e-6f));
    lv = lv < 0 ? 0 : (lv > 3 ? 3 : lv);

    const float* fbase; int H, W; float sc;
    switch (lv) {
        case 0:  fbase = f0; H = 200; W = 304; sc = 0.25f;    break;
        case 1:  fbase = f1; H = 100; W = 152; sc = 0.125f;   break;
        case 2:  fbase = f2; H = 50;  W = 76;  sc = 0.0625f;  break;
        default: fbase = f3; H = 25;  W = 38;  sc = 0.03125f; break;
    }
    const int HW = H * W;

    const float y1s = ry1 * sc;
    const float roih = fmaxf(ry2 * sc - y1s, 1.0f);
    const float x1s = rx1 * sc;
    const float roiw = fmaxf(rx2 * sc - x1s, 1.0f);
    const float ystep = roih / (float)OUTS;
    const float xstep = roiw / (float)OUTS;

    // ---- window bounds (uniform; same formulas as taps -> consistent) ----
    // sample s: coord = start + (s+0.5)*0.5*step ; s=0 -> 0.25, s=13 -> 6.75
    const float ysA = y1s + 0.25f * ystep, ysZ = y1s + 6.75f * ystep;
    const float xsA = x1s + 0.25f * xstep, xsZ = x1s + 6.75f * xstep;
    const int ylo = (int)floorf(fminf(fmaxf(ysA, 0.0f), (float)(H - 1)));
    const int yhi = min((int)floorf(fminf(fmaxf(ysZ, 0.0f), (float)(H - 1))) + 1, H - 1);
    const int xlo = (int)floorf(fminf(fmaxf(xsA, 0.0f), (float)(W - 1)));
    const int xhi = min((int)floorf(fminf(fmaxf(xsZ, 0.0f), (float)(W - 1))) + 1, W - 1);
    const int Ww = xhi - xlo + 1;
    const int Hw = yhi - ylo + 1;
    const int E = Ww * Hw;
    const bool useLds = (E <= LDSW);
    const int stride = useLds ? Ww : W;
    const int obase  = useLds ? 0 : (ylo * W + xlo);

    // ---- per-bin taps (window-relative), computed once, reused over channels ----
    const int oh = bin / OUTS;
    const int ow = bin - oh * OUTS;

    int ry0[2], ry1i[2]; float wy[2], vy[2];
#pragma unroll
    for (int py = 0; py < 2; ++py) {
        const float g = ((float)(oh * 2 + py) + 0.5f) * 0.5f;
        const float ys = y1s + g * ystep;
        vy[py] = (ys >= -1.0f && ys <= (float)H) ? 1.0f : 0.0f;
        const float y = fminf(fmaxf(ys, 0.0f), (float)(H - 1));
        const float y0f = floorf(y);
        const int y0 = (int)y0f;
        ry0[py]  = y0 - ylo;
        ry1i[py] = min(y0 + 1, H - 1) - ylo;
        wy[py] = y - y0f;
    }
    int rx0[2], rx1i[2]; float wx[2], vx[2];
#pragma unroll
    for (int px = 0; px < 2; ++px) {
        const float g = ((float)(ow * 2 + px) + 0.5f) * 0.5f;
        const float xs = x1s + g * xstep;
        vx[px] = (xs >= -1.0f && xs <= (float)W) ? 1.0f : 0.0f;
        const float x = fminf(fmaxf(xs, 0.0f), (float)(W - 1));
        const float x0f = floorf(x);
        const int x0 = (int)x0f;
        rx0[px]  = x0 - xlo;
        rx1i[px] = min(x0 + 1, W - 1) - xlo;
        wx[px] = x - x0f;
    }

    int off[16]; float wt[16];
#pragma unroll
    for (int py = 0; py < 2; ++py) {
#pragma unroll
        for (int px = 0; px < 2; ++px) {
            const int i = (py * 2 + px) * 4;
            const float v = vy[py] * vx[px] * 0.25f;
            const float a = wy[py], b = wx[px];
            off[i + 0] = ry0[py]  * stride + rx0[px]  + obase; wt[i + 0] = (1.0f - a) * (1.0f - b) * v;
            off[i + 1] = ry0[py]  * stride + rx1i[px] + obase; wt[i + 1] = (1.0f - a) * b * v;
            off[i + 2] = ry1i[py] * stride + rx0[px]  + obase; wt[i + 2] = a * (1.0f - b) * v;
            off[i + 3] = ry1i[py] * stride + rx1i[px] + obase; wt[i + 3] = a * b * v;
        }
    }

    // ---- per-wave channel-pair loop; wave-private LDS, no barriers ----
    __shared__ float2 lds2[4 * LDSW];
    float2* const myw = &lds2[wid * LDSW];
    const float inv_Ww = 1.0f / (float)Ww;

#pragma unroll
    for (int j = 0; j < 4; ++j) {
        const int chA = cbase + wid * 8 + j * 2;
        const float* sA = fbase + (size_t)chA * HW + (size_t)ylo * W + xlo;
        const float* sB = sA + HW;

        if (useLds) {
            // stage: coalesced row segments, channel-interleaved float2
            for (int e = lane; e < E; e += 64) {
                const int r = (int)(((float)e + 0.5f) * inv_Ww);
                const int g = r * W + (e - r * Ww);
                myw[e] = make_float2(sA[g], sB[g]);
            }
            if (lane < NBIN) {
                float ax = 0.0f, ay = 0.0f;
#pragma unroll
                for (int i = 0; i < 16; ++i) {
                    const float2 v = myw[off[i]];
                    ax += v.x * wt[i];
                    ay += v.y * wt[i];
                }
                float* outA = out + ((size_t)k * NCH + chA) * NBIN + bin;
                outA[0] = ax;
                outA[NBIN] = ay;
            }
        } else {
            // uniform fallback: direct global gather (never taken for this dataset)
            if (lane < NBIN) {
                const float* pA = fbase + (size_t)chA * HW;
                const float* pB = pA + HW;
                float ax = 0.0f, ay = 0.0f;
#pragma unroll
                for (int i = 0; i < 16; ++i) {
                    ax += pA[off[i]] * wt[i];
                    ay += pB[off[i]] * wt[i];
                }
                float* outA = out + ((size_t)k * NCH + chA) * NBIN + bin;
                outA[0] = ax;
                outA[NBIN] = ay;
            }
        }
    }
}

extern "C" void kernel_launch(void* const* d_in, const int* in_sizes, int n_in,
                              void* d_out, int out_size, void* d_ws, size_t ws_size,
                              hipStream_t stream) {
    const float* f0 = (const float*)d_in[0];
    const float* f1 = (const float*)d_in[1];
    const float* f2 = (const float*)d_in[2];
    const float* f3 = (const float*)d_in[3];
    const float* rois = (const float*)d_in[4];
    float* out = (float*)d_out;
    int K = in_sizes[4] / 4;
    if (K <= 0) return;

    dim3 grid(K, NCH / CPB);   // (1024, 8)
    roi_extract_kernel<<<grid, 256, 0, stream>>>(f0, f1, f2, f3, rois, out, K);
}

// Round 6
// 202.400 us; speedup vs baseline: 1.5756x; 1.1259x over previous
//
#include <hip/hip_runtime.h>
#include <math.h>

#define OUTS 7
#define NBIN 49
#define NCH 256
#define LDSW 1200        // fallback kernel: float2 elems per wave window

// Channels-last workspace offsets (floats)
#define O1 15564800ull                  // 60800*256
#define O2 19456000ull                  // O1 + 15200*256
#define O3 20428800ull                  // O2 + 3800*256
#define WS_FLOATS 20672000ull           // O3 + 950*256
#define WS_BYTES  (WS_FLOATS * 4ull)

// ---------------- transpose: [C][H][W] -> [HW][C] (channels-last) ----------------
// grid (1263, 4), block 256. 64x64 tiles; level resolved from blockIdx.x.
__global__ __launch_bounds__(256) void transpose_cl(
    const float* __restrict__ f0, const float* __restrict__ f1,
    const float* __restrict__ f2, const float* __restrict__ f3,
    float* __restrict__ ws)
{
    const int bt = blockIdx.x;
    const int cb = blockIdx.y * 64;
    const float* src; float* dst; int HW, t0;
    if (bt < 950)       { src = f0; dst = ws;      HW = 60800; t0 = bt; }
    else if (bt < 1188) { src = f1; dst = ws + O1; HW = 15200; t0 = bt - 950; }
    else if (bt < 1248) { src = f2; dst = ws + O2; HW = 3800;  t0 = bt - 1188; }
    else                { src = f3; dst = ws + O3; HW = 950;   t0 = bt - 1248; }
    const int hw0 = t0 * 64;

    __shared__ float tile[64][65];
    const int tx = threadIdx.x & 63;
    const int ty = threadIdx.x >> 6;    // 0..3

#pragma unroll
    for (int j = 0; j < 16; ++j) {
        const int c = cb + ty + 4 * j;
        const int hw = hw0 + tx;
        tile[ty + 4 * j][tx] = (hw < HW) ? src[(size_t)c * HW + hw] : 0.0f;
    }
    __syncthreads();
#pragma unroll
    for (int j = 0; j < 16; ++j) {
        const int hw = hw0 + ty + 4 * j;
        if (hw < HW) dst[(size_t)hw * 256 + cb + tx] = tile[tx][ty + 4 * j];
    }
}

// ---------------- main: coalesced taps from channels-last features ----------------
// grid (K, 4): block = one RoI x 64 channels; 4 waves split the 49 bins.
__global__ __launch_bounds__(256) void roi_main(
    const float* __restrict__ ws, const float* __restrict__ rois,
    float* __restrict__ out, int K)
{
    const int k = blockIdx.x;
    const int cbase = blockIdx.y * 64;
    const int tid = threadIdx.x;
    const int wid = tid >> 6;
    const int lane = tid & 63;

    const float rx1 = rois[0 * K + k];
    const float ry1 = rois[1 * K + k];
    const float rx2 = rois[2 * K + k];
    const float ry2 = rois[3 * K + k];

    const float sroi = sqrtf((rx2 - rx1 + 1.0f) * (ry2 - ry1 + 1.0f));
    int lv = (int)floorf(log2f(sroi / 56.0f + 1e-6f));
    lv = lv < 0 ? 0 : (lv > 3 ? 3 : lv);

    const float* wb; int H, W; float sc;
    switch (lv) {
        case 0:  wb = ws;      H = 200; W = 304; sc = 0.25f;    break;
        case 1:  wb = ws + O1; H = 100; W = 152; sc = 0.125f;   break;
        case 2:  wb = ws + O2; H = 50;  W = 76;  sc = 0.0625f;  break;
        default: wb = ws + O3; H = 25;  W = 38;  sc = 0.03125f; break;
    }

    const float y1s = ry1 * sc;
    const float ystep = fmaxf(ry2 * sc - y1s, 1.0f) / (float)OUTS;
    const float x1s = rx1 * sc;
    const float xstep = fmaxf(rx2 * sc - x1s, 1.0f) / (float)OUTS;

    __shared__ float obuf[64 * NBIN];   // [channel][bin], 12.25 KB
    const float* wbl = wb + cbase + lane;   // lane = channel

    const int bin_lo = wid * 13;
    const int bin_hi = (bin_lo + 13 < NBIN) ? bin_lo + 13 : NBIN;
    for (int bin = bin_lo; bin < bin_hi; ++bin) {
        const int oh = bin / OUTS;
        const int ow = bin - oh * OUTS;

        int y0i[2], y1i[2]; float wyv[2], vyv[2];
#pragma unroll
        for (int p = 0; p < 2; ++p) {
            const float g = ((float)(oh * 2 + p) + 0.5f) * 0.5f;
            const float ysv = y1s + g * ystep;
            vyv[p] = (ysv >= -1.0f && ysv <= (float)H) ? 1.0f : 0.0f;
            const float y = fminf(fmaxf(ysv, 0.0f), (float)(H - 1));
            const float yf = floorf(y);
            const int y0 = (int)yf;
            y0i[p] = y0;
            y1i[p] = min(y0 + 1, H - 1);
            wyv[p] = y - yf;
        }
        int x0i[2], x1i[2]; float wxv[2], vxv[2];
#pragma unroll
        for (int p = 0; p < 2; ++p) {
            const float g = ((float)(ow * 2 + p) + 0.5f) * 0.5f;
            const float xsv = x1s + g * xstep;
            vxv[p] = (xsv >= -1.0f && xsv <= (float)W) ? 1.0f : 0.0f;
            const float x = fminf(fmaxf(xsv, 0.0f), (float)(W - 1));
            const float xf = floorf(x);
            const int x0 = (int)xf;
            x0i[p] = x0;
            x1i[p] = min(x0 + 1, W - 1);
            wxv[p] = x - xf;
        }

        int off[16]; float wt[16];
#pragma unroll
        for (int py = 0; py < 2; ++py) {
#pragma unroll
            for (int px = 0; px < 2; ++px) {
                const int i = (py * 2 + px) * 4;
                const float v = vyv[py] * vxv[px] * 0.25f;
                const float a = wyv[py], b = wxv[px];
                off[i + 0] = y0i[py] * W + x0i[px]; wt[i + 0] = (1.0f - a) * (1.0f - b) * v;
                off[i + 1] = y0i[py] * W + x1i[px]; wt[i + 1] = (1.0f - a) * b * v;
                off[i + 2] = y1i[py] * W + x0i[px]; wt[i + 2] = a * (1.0f - b) * v;
                off[i + 3] = y1i[py] * W + x1i[px]; wt[i + 3] = a * b * v;
            }
        }

        float acc = 0.0f;
#pragma unroll
        for (int i = 0; i < 16; ++i)
            acc += wbl[(size_t)off[i] * 256] * wt[i];   // coalesced 256B wave-load

        obuf[lane * NBIN + bin] = acc;   // stride 49: 2-way alias, free
    }
    __syncthreads();

    // block-contiguous store of 64ch x 49bins = 12544 B
    float* dst = out + ((size_t)k * NCH + cbase) * NBIN;
    for (int i = tid; i < 64 * NBIN; i += 256) dst[i] = obuf[i];
}

// ---------------- fallback (Round-5 kernel) if ws too small ----------------
__global__ __launch_bounds__(256) void roi_extract_fallback(
    const float* __restrict__ f0, const float* __restrict__ f1,
    const float* __restrict__ f2, const float* __restrict__ f3,
    const float* __restrict__ rois, float* __restrict__ out, int K)
{
    const int k = blockIdx.x;
    if (k >= K) return;
    const int cbase = blockIdx.y * 32;
    const int tid = threadIdx.x;
    const int wid = tid >> 6;
    const int lane = tid & 63;
    const int bin = lane < NBIN ? lane : NBIN - 1;

    const float rx1 = rois[0 * K + k];
    const float ry1 = rois[1 * K + k];
    const float rx2 = rois[2 * K + k];
    const float ry2 = rois[3 * K + k];

    const float sroi = sqrtf((rx2 - rx1 + 1.0f) * (ry2 - ry1 + 1.0f));
    int lv = (int)floorf(log2f(sroi / 56.0f + 1e-6f));
    lv = lv < 0 ? 0 : (lv > 3 ? 3 : lv);

    const float* fbase; int H, W; float sc;
    switch (lv) {
        case 0:  fbase = f0; H = 200; W = 304; sc = 0.25f;    break;
        case 1:  fbase = f1; H = 100; W = 152; sc = 0.125f;   break;
        case 2:  fbase = f2; H = 50;  W = 76;  sc = 0.0625f;  break;
        default: fbase = f3; H = 25;  W = 38;  sc = 0.03125f; break;
    }
    const int HW = H * W;

    const float y1s = ry1 * sc;
    const float roih = fmaxf(ry2 * sc - y1s, 1.0f);
    const float x1s = rx1 * sc;
    const float roiw = fmaxf(rx2 * sc - x1s, 1.0f);
    const float ystep = roih / (float)OUTS;
    const float xstep = roiw / (float)OUTS;

    const float ysA = y1s + 0.25f * ystep, ysZ = y1s + 6.75f * ystep;
    const float xsA = x1s + 0.25f * xstep, xsZ = x1s + 6.75f * xstep;
    const int ylo = (int)floorf(fminf(fmaxf(ysA, 0.0f), (float)(H - 1)));
    const int xlo = (int)floorf(fminf(fmaxf(xsA, 0.0f), (float)(W - 1)));
    const int xhi = min((int)floorf(fminf(fmaxf(xsZ, 0.0f), (float)(W - 1))) + 1, W - 1);
    const int yhi = min((int)floorf(fminf(fmaxf(ysZ, 0.0f), (float)(H - 1))) + 1, H - 1);
    const int Ww = xhi - xlo + 1;
    const int Hw = yhi - ylo + 1;
    const int E = Ww * Hw;
    const bool useLds = (E <= LDSW);
    const int stride = useLds ? Ww : W;
    const int obase  = useLds ? 0 : (ylo * W + xlo);

    const int oh = bin / OUTS;
    const int ow = bin - oh * OUTS;

    int ry0[2], ry1i[2]; float wy[2], vy[2];
#pragma unroll
    for (int py = 0; py < 2; ++py) {
        const float g = ((float)(oh * 2 + py) + 0.5f) * 0.5f;
        const float ys = y1s + g * ystep;
        vy[py] = (ys >= -1.0f && ys <= (float)H) ? 1.0f : 0.0f;
        const float y = fminf(fmaxf(ys, 0.0f), (float)(H - 1));
        const float y0f = floorf(y);
        const int y0 = (int)y0f;
        ry0[py]  = y0 - ylo;
        ry1i[py] = min(y0 + 1, H - 1) - ylo;
        wy[py] = y - y0f;
    }
    int rx0[2], rx1i[2]; float wx[2], vx[2];
#pragma unroll
    for (int px = 0; px < 2; ++px) {
        const float g = ((float)(ow * 2 + px) + 0.5f) * 0.5f;
        const float xs = x1s + g * xstep;
        vx[px] = (xs >= -1.0f && xs <= (float)W) ? 1.0f : 0.0f;
        const float x = fminf(fmaxf(xs, 0.0f), (float)(W - 1));
        const float x0f = floorf(x);
        const int x0 = (int)x0f;
        rx0[px]  = x0 - xlo;
        rx1i[px] = min(x0 + 1, W - 1) - xlo;
        wx[px] = x - x0f;
    }

    int off[16]; float wt[16];
#pragma unroll
    for (int py = 0; py < 2; ++py) {
#pragma unroll
        for (int px = 0; px < 2; ++px) {
            const int i = (py * 2 + px) * 4;
            const float v = vy[py] * vx[px] * 0.25f;
            const float a = wy[py], b = wx[px];
            off[i + 0] = ry0[py]  * stride + rx0[px]  + obase; wt[i + 0] = (1.0f - a) * (1.0f - b) * v;
            off[i + 1] = ry0[py]  * stride + rx1i[px] + obase; wt[i + 1] = (1.0f - a) * b * v;
            off[i + 2] = ry1i[py] * stride + rx0[px]  + obase; wt[i + 2] = a * (1.0f - b) * v;
            off[i + 3] = ry1i[py] * stride + rx1i[px] + obase; wt[i + 3] = a * b * v;
        }
    }

    __shared__ float2 lds2[4 * LDSW];
    float2* const myw = &lds2[wid * LDSW];
    const float inv_Ww = 1.0f / (float)Ww;

#pragma unroll
    for (int j = 0; j < 4; ++j) {
        const int chA = cbase + wid * 8 + j * 2;
        const float* sA = fbase + (size_t)chA * HW + (size_t)ylo * W + xlo;
        const float* sB = sA + HW;

        if (useLds) {
            for (int e = lane; e < E; e += 64) {
                const int r = (int)(((float)e + 0.5f) * inv_Ww);
                const int g = r * W + (e - r * Ww);
                myw[e] = make_float2(sA[g], sB[g]);
            }
            if (lane < NBIN) {
                float ax = 0.0f, ay = 0.0f;
#pragma unroll
                for (int i = 0; i < 16; ++i) {
                    const float2 v = myw[off[i]];
                    ax += v.x * wt[i];
                    ay += v.y * wt[i];
                }
                float* outA = out + ((size_t)k * NCH + chA) * NBIN + bin;
                outA[0] = ax;
                outA[NBIN] = ay;
            }
        } else {
            if (lane < NBIN) {
                const float* pA = fbase + (size_t)chA * HW;
                const float* pB = pA + HW;
                float ax = 0.0f, ay = 0.0f;
#pragma unroll
                for (int i = 0; i < 16; ++i) {
                    ax += pA[off[i]] * wt[i];
                    ay += pB[off[i]] * wt[i];
                }
                float* outA = out + ((size_t)k * NCH + chA) * NBIN + bin;
                outA[0] = ax;
                outA[NBIN] = ay;
            }
        }
    }
}

extern "C" void kernel_launch(void* const* d_in, const int* in_sizes, int n_in,
                              void* d_out, int out_size, void* d_ws, size_t ws_size,
                              hipStream_t stream) {
    const float* f0 = (const float*)d_in[0];
    const float* f1 = (const float*)d_in[1];
    const float* f2 = (const float*)d_in[2];
    const float* f3 = (const float*)d_in[3];
    const float* rois = (const float*)d_in[4];
    float* out = (float*)d_out;
    int K = in_sizes[4] / 4;
    if (K <= 0) return;

    if (ws_size >= WS_BYTES) {
        float* ws = (float*)d_ws;
        transpose_cl<<<dim3(1263, 4), 256, 0, stream>>>(f0, f1, f2, f3, ws);
        roi_main<<<dim3(K, 4), 256, 0, stream>>>(ws, rois, out, K);
    } else {
        roi_extract_fallback<<<dim3(K, 8), 256, 0, stream>>>(f0, f1, f2, f3, rois, out, K);
    }
}

// Round 7
// 189.126 us; speedup vs baseline: 1.6862x; 1.0702x over previous
//
#include <hip/hip_runtime.h>
#include <math.h>

#define OUTS 7
#define NBIN 49
#define NCH 256
#define LDSW 1200        // fallback kernel: float2 elems per wave window
#define OBS 132          // obuf stride (floats): even -> aligned float2 writes

// Channels-last workspace offsets (floats)
#define O1 15564800ull                  // 60800*256
#define O2 19456000ull                  // O1 + 15200*256
#define O3 20428800ull                  // O2 + 3800*256
#define WS_FLOATS 20672000ull           // O3 + 950*256
#define WS_BYTES  (WS_FLOATS * 4ull)

// ---------------- transpose: [C][H][W] -> [HW][C] (channels-last) ----------------
__global__ __launch_bounds__(256) void transpose_cl(
    const float* __restrict__ f0, const float* __restrict__ f1,
    const float* __restrict__ f2, const float* __restrict__ f3,
    float* __restrict__ ws)
{
    const int bt = blockIdx.x;
    const int cb = blockIdx.y * 64;
    const float* src; float* dst; int HW, t0;
    if (bt < 950)       { src = f0; dst = ws;      HW = 60800; t0 = bt; }
    else if (bt < 1188) { src = f1; dst = ws + O1; HW = 15200; t0 = bt - 950; }
    else if (bt < 1248) { src = f2; dst = ws + O2; HW = 3800;  t0 = bt - 1188; }
    else                { src = f3; dst = ws + O3; HW = 950;   t0 = bt - 1248; }
    const int hw0 = t0 * 64;

    __shared__ float tile[64][65];
    const int tx = threadIdx.x & 63;
    const int ty = threadIdx.x >> 6;    // 0..3

#pragma unroll
    for (int j = 0; j < 16; ++j) {
        const int c = cb + ty + 4 * j;
        const int hw = hw0 + tx;
        tile[ty + 4 * j][tx] = (hw < HW) ? src[(size_t)c * HW + hw] : 0.0f;
    }
    __syncthreads();
#pragma unroll
    for (int j = 0; j < 16; ++j) {
        const int hw = hw0 + ty + 4 * j;
        if (hw < HW) dst[(size_t)hw * 256 + cb + tx] = tile[tx][ty + 4 * j];
    }
}

// ---------------- main: LDS axis tables + float2 channel-pairs ----------------
// grid (K, 2): block = one RoI x 128 channels; lane = channel-pair; wave takes
// bins w, w+4, ... (12-13 each).
__global__ __launch_bounds__(256) void roi_main(
    const float* __restrict__ ws, const float* __restrict__ rois,
    float* __restrict__ out, int K)
{
    const int k = blockIdx.x;
    const int cbase = blockIdx.y * 128;
    const int tid = threadIdx.x;
    const int wid = tid >> 6;
    const int lane = tid & 63;

    const float rx1 = rois[0 * K + k];
    const float ry1 = rois[1 * K + k];
    const float rx2 = rois[2 * K + k];
    const float ry2 = rois[3 * K + k];

    const float sroi = sqrtf((rx2 - rx1 + 1.0f) * (ry2 - ry1 + 1.0f));
    int lv = (int)floorf(log2f(sroi / 56.0f + 1e-6f));
    lv = lv < 0 ? 0 : (lv > 3 ? 3 : lv);

    const float* wb; int H, W; float sc;
    switch (lv) {
        case 0:  wb = ws;      H = 200; W = 304; sc = 0.25f;    break;
        case 1:  wb = ws + O1; H = 100; W = 152; sc = 0.125f;   break;
        case 2:  wb = ws + O2; H = 50;  W = 76;  sc = 0.0625f;  break;
        default: wb = ws + O3; H = 25;  W = 38;  sc = 0.03125f; break;
    }

    const float y1s = ry1 * sc;
    const float ystep = fmaxf(ry2 * sc - y1s, 1.0f) / (float)OUTS;
    const float x1s = rx1 * sc;
    const float xstep = fmaxf(rx2 * sc - x1s, 1.0f) / (float)OUTS;

    // Per-axis node tables: 14 samples -> (node0 off, node1 off, w0, w1); 0.5
    // folded per axis so tap weight = yw*xw carries the 0.25 sample average.
    __shared__ int2   syo[14];  __shared__ float2 syw[14];
    __shared__ int2   sxo[14];  __shared__ float2 sxw[14];
    __shared__ float  obuf[NBIN * OBS];   // [bin][channel], padded

    if (tid < 14) {
        const int s = tid;
        const float g = ((float)s + 0.5f) * 0.5f;
        const float ysv = y1s + g * ystep;
        const float v = (ysv >= -1.0f && ysv <= (float)H) ? 0.5f : 0.0f;
        const float y = fminf(fmaxf(ysv, 0.0f), (float)(H - 1));
        const float yf = floorf(y);
        const int y0 = (int)yf;
        const float wy = y - yf;
        syo[s] = make_int2(y0 * W, min(y0 + 1, H - 1) * W);
        syw[s] = make_float2((1.0f - wy) * v, wy * v);
    } else if (tid < 28) {
        const int s = tid - 14;
        const float g = ((float)s + 0.5f) * 0.5f;
        const float xsv = x1s + g * xstep;
        const float v = (xsv >= -1.0f && xsv <= (float)W) ? 0.5f : 0.0f;
        const float x = fminf(fmaxf(xsv, 0.0f), (float)(W - 1));
        const float xf = floorf(x);
        const int x0 = (int)xf;
        const float wx = x - xf;
        sxo[s] = make_int2(x0, min(x0 + 1, W - 1));
        sxw[s] = make_float2((1.0f - wx) * v, wx * v);
    }
    __syncthreads();

    const float* wbl = wb + cbase + 2 * lane;   // lane = channel pair

    for (int b = wid; b < NBIN; b += 4) {
        const int oh = b / OUTS;
        const int ow = b - oh * OUTS;

        const int2   ya = syo[2 * oh], yb = syo[2 * oh + 1];
        const float2 wa = syw[2 * oh], wbv = syw[2 * oh + 1];
        const int2   xa = sxo[2 * ow], xb = sxo[2 * ow + 1];
        const float2 ua = sxw[2 * ow], ub = sxw[2 * ow + 1];

        const int   yo[4] = { ya.x, ya.y, yb.x, yb.y };
        const float yw[4] = { wa.x, wa.y, wbv.x, wbv.y };
        const int   xo[4] = { xa.x, xa.y, xb.x, xb.y };
        const float xw[4] = { ua.x, ua.y, ub.x, ub.y };

        float a0 = 0.0f, a1 = 0.0f;
#pragma unroll
        for (int iy = 0; iy < 4; ++iy) {
#pragma unroll
            for (int ix = 0; ix < 4; ++ix) {
                const float2 v = *(const float2*)(wbl + ((size_t)(yo[iy] + xo[ix]) << 8));
                const float wv = yw[iy] * xw[ix];
                a0 += v.x * wv;
                a1 += v.y * wv;
            }
        }
        *(float2*)(&obuf[b * OBS + 2 * lane]) = make_float2(a0, a1);
    }
    __syncthreads();

    // contiguous 128ch x 49bin block store
    float* dst = out + ((size_t)k * NCH + cbase) * NBIN;
    for (int i = tid; i < 128 * NBIN; i += 256) {
        const int c = i / NBIN;
        const int b = i - c * NBIN;
        dst[i] = obuf[b * OBS + c];
    }
}

// ---------------- fallback (Round-5 kernel) if ws too small ----------------
__global__ __launch_bounds__(256) void roi_extract_fallback(
    const float* __restrict__ f0, const float* __restrict__ f1,
    const float* __restrict__ f2, const float* __restrict__ f3,
    const float* __restrict__ rois, float* __restrict__ out, int K)
{
    const int k = blockIdx.x;
    if (k >= K) return;
    const int cbase = blockIdx.y * 32;
    const int tid = threadIdx.x;
    const int wid = tid >> 6;
    const int lane = tid & 63;
    const int bin = lane < NBIN ? lane : NBIN - 1;

    const float rx1 = rois[0 * K + k];
    const float ry1 = rois[1 * K + k];
    const float rx2 = rois[2 * K + k];
    const float ry2 = rois[3 * K + k];

    const float sroi = sqrtf((rx2 - rx1 + 1.0f) * (ry2 - ry1 + 1.0f));
    int lv = (int)floorf(log2f(sroi / 56.0f + 1e-6f));
    lv = lv < 0 ? 0 : (lv > 3 ? 3 : lv);

    const float* fbase; int H, W; float sc;
    switch (lv) {
        case 0:  fbase = f0; H = 200; W = 304; sc = 0.25f;    break;
        case 1:  fbase = f1; H = 100; W = 152; sc = 0.125f;   break;
        case 2:  fbase = f2; H = 50;  W = 76;  sc = 0.0625f;  break;
        default: fbase = f3; H = 25;  W = 38;  sc = 0.03125f; break;
    }
    const int HW = H * W;

    const float y1s = ry1 * sc;
    const float roih = fmaxf(ry2 * sc - y1s, 1.0f);
    const float x1s = rx1 * sc;
    const float roiw = fmaxf(rx2 * sc - x1s, 1.0f);
    const float ystep = roih / (float)OUTS;
    const float xstep = roiw / (float)OUTS;

    const float ysA = y1s + 0.25f * ystep, ysZ = y1s + 6.75f * ystep;
    const float xsA = x1s + 0.25f * xstep, xsZ = x1s + 6.75f * xstep;
    const int ylo = (int)floorf(fminf(fmaxf(ysA, 0.0f), (float)(H - 1)));
    const int xlo = (int)floorf(fminf(fmaxf(xsA, 0.0f), (float)(W - 1)));
    const int xhi = min((int)floorf(fminf(fmaxf(xsZ, 0.0f), (float)(W - 1))) + 1, W - 1);
    const int yhi = min((int)floorf(fminf(fmaxf(ysZ, 0.0f), (float)(H - 1))) + 1, H - 1);
    const int Ww = xhi - xlo + 1;
    const int Hw = yhi - ylo + 1;
    const int E = Ww * Hw;
    const bool useLds = (E <= LDSW);
    const int stride = useLds ? Ww : W;
    const int obase  = useLds ? 0 : (ylo * W + xlo);

    const int oh = bin / OUTS;
    const int ow = bin - oh * OUTS;

    int ry0[2], ry1i[2]; float wy[2], vy[2];
#pragma unroll
    for (int py = 0; py < 2; ++py) {
        const float g = ((float)(oh * 2 + py) + 0.5f) * 0.5f;
        const float ys = y1s + g * ystep;
        vy[py] = (ys >= -1.0f && ys <= (float)H) ? 1.0f : 0.0f;
        const float y = fminf(fmaxf(ys, 0.0f), (float)(H - 1));
        const float y0f = floorf(y);
        const int y0 = (int)y0f;
        ry0[py]  = y0 - ylo;
        ry1i[py] = min(y0 + 1, H - 1) - ylo;
        wy[py] = y - y0f;
    }
    int rx0[2], rx1i[2]; float wx[2], vx[2];
#pragma unroll
    for (int px = 0; px < 2; ++px) {
        const float g = ((float)(ow * 2 + px) + 0.5f) * 0.5f;
        const float xs = x1s + g * xstep;
        vx[px] = (xs >= -1.0f && xs <= (float)W) ? 1.0f : 0.0f;
        const float x = fminf(fmaxf(xs, 0.0f), (float)(W - 1));
        const float x0f = floorf(x);
        const int x0 = (int)x0f;
        rx0[px]  = x0 - xlo;
        rx1i[px] = min(x0 + 1, W - 1) - xlo;
        wx[px] = x - x0f;
    }

    int off[16]; float wt[16];
#pragma unroll
    for (int py = 0; py < 2; ++py) {
#pragma unroll
        for (int px = 0; px < 2; ++px) {
            const int i = (py * 2 + px) * 4;
            const float v = vy[py] * vx[px] * 0.25f;
            const float a = wy[py], b = wx[px];
            off[i + 0] = ry0[py]  * stride + rx0[px]  + obase; wt[i + 0] = (1.0f - a) * (1.0f - b) * v;
            off[i + 1] = ry0[py]  * stride + rx1i[px] + obase; wt[i + 1] = (1.0f - a) * b * v;
            off[i + 2] = ry1i[py] * stride + rx0[px]  + obase; wt[i + 2] = a * (1.0f - b) * v;
            off[i + 3] = ry1i[py] * stride + rx1i[px] + obase; wt[i + 3] = a * b * v;
        }
    }

    __shared__ float2 lds2[4 * LDSW];
    float2* const myw = &lds2[wid * LDSW];
    const float inv_Ww = 1.0f / (float)Ww;

#pragma unroll
    for (int j = 0; j < 4; ++j) {
        const int chA = cbase + wid * 8 + j * 2;
        const float* sA = fbase + (size_t)chA * HW + (size_t)ylo * W + xlo;
        const float* sB = sA + HW;

        if (useLds) {
            for (int e = lane; e < E; e += 64) {
                const int r = (int)(((float)e + 0.5f) * inv_Ww);
                const int g = r * W + (e - r * Ww);
                myw[e] = make_float2(sA[g], sB[g]);
            }
            if (lane < NBIN) {
                float ax = 0.0f, ay = 0.0f;
#pragma unroll
                for (int i = 0; i < 16; ++i) {
                    const float2 v = myw[off[i]];
                    ax += v.x * wt[i];
                    ay += v.y * wt[i];
                }
                float* outA = out + ((size_t)k * NCH + chA) * NBIN + bin;
                outA[0] = ax;
                outA[NBIN] = ay;
            }
        } else {
            if (lane < NBIN) {
                const float* pA = fbase + (size_t)chA * HW;
                const float* pB = pA + HW;
                float ax = 0.0f, ay = 0.0f;
#pragma unroll
                for (int i = 0; i < 16; ++i) {
                    ax += pA[off[i]] * wt[i];
                    ay += pB[off[i]] * wt[i];
                }
                float* outA = out + ((size_t)k * NCH + chA) * NBIN + bin;
                outA[0] = ax;
                outA[NBIN] = ay;
            }
        }
    }
}

extern "C" void kernel_launch(void* const* d_in, const int* in_sizes, int n_in,
                              void* d_out, int out_size, void* d_ws, size_t ws_size,
                              hipStream_t stream) {
    const float* f0 = (const float*)d_in[0];
    const float* f1 = (const float*)d_in[1];
    const float* f2 = (const float*)d_in[2];
    const float* f3 = (const float*)d_in[3];
    const float* rois = (const float*)d_in[4];
    float* out = (float*)d_out;
    int K = in_sizes[4] / 4;
    if (K <= 0) return;

    if (ws_size >= WS_BYTES) {
        float* ws = (float*)d_ws;
        transpose_cl<<<dim3(1263, 4), 256, 0, stream>>>(f0, f1, f2, f3, ws);
        roi_main<<<dim3(K, 2), 256, 0, stream>>>(ws, rois, out, K);
    } else {
        roi_extract_fallback<<<dim3(K, 8), 256, 0, stream>>>(f0, f1, f2, f3, rois, out, K);
    }
}